// Round 1
// baseline (1885.116 us; speedup 1.0000x reference)
//
#include <hip/hip_runtime.h>
#include <cstddef>

#define Bsz    2
#define Lseq   2048
#define Dmodel 1024
#define NHEAD  16
#define DPH    64
#define NGRP   32          // B*H
#define MROWS  4096        // B*L
#define EPS_LN 1e-5f

// ---------------------------------------------------------------------------
// GEMM: out[M,N] = X[M,K] @ W[N,K]^T + bias (+ resid)     (torch Linear)
// Tiles: 128x128, BK=16, 256 threads, 8x8 per thread. fp32 VALU.
// ---------------------------------------------------------------------------
template<bool RESID>
__global__ __launch_bounds__(256) void gemm_bias(
    const float* __restrict__ X, const float* __restrict__ W,
    const float* __restrict__ bias, const float* __restrict__ resid,
    float* __restrict__ out, int Kdim, int Ndim)
{
    __shared__ float Xs[128][17];
    __shared__ float Ws[128][17];
    const int t  = threadIdx.x;
    const int m0 = blockIdx.y * 128;
    const int n0 = blockIdx.x * 128;
    const int tr = t >> 4, tc = t & 15;

    float acc[8][8] = {};

    for (int k0 = 0; k0 < Kdim; k0 += 16) {
#pragma unroll
        for (int it = 0; it < 2; ++it) {
            int id  = t + it * 256;          // 0..511
            int row = id >> 2;               // 0..127
            int c4  = (id & 3) * 4;          // 0,4,8,12
            float4 xv = *reinterpret_cast<const float4*>(X + (size_t)(m0 + row) * Kdim + k0 + c4);
            float4 wv = *reinterpret_cast<const float4*>(W + (size_t)(n0 + row) * Kdim + k0 + c4);
            Xs[row][c4 + 0] = xv.x; Xs[row][c4 + 1] = xv.y;
            Xs[row][c4 + 2] = xv.z; Xs[row][c4 + 3] = xv.w;
            Ws[row][c4 + 0] = wv.x; Ws[row][c4 + 1] = wv.y;
            Ws[row][c4 + 2] = wv.z; Ws[row][c4 + 3] = wv.w;
        }
        __syncthreads();
#pragma unroll
        for (int kk = 0; kk < 16; ++kk) {
            float a[8], b[8];
#pragma unroll
            for (int i = 0; i < 8; ++i) a[i] = Xs[tr * 8 + i][kk];
#pragma unroll
            for (int j = 0; j < 8; ++j) b[j] = Ws[tc * 8 + j][kk];
#pragma unroll
            for (int i = 0; i < 8; ++i)
#pragma unroll
                for (int j = 0; j < 8; ++j)
                    acc[i][j] = fmaf(a[i], b[j], acc[i][j]);
        }
        __syncthreads();
    }

#pragma unroll
    for (int i = 0; i < 8; ++i) {
        int row = m0 + tr * 8 + i;
#pragma unroll
        for (int j4 = 0; j4 < 8; j4 += 4) {
            int col = n0 + tc * 8 + j4;
            float4 o;
            o.x = acc[i][j4 + 0] + bias[col + 0];
            o.y = acc[i][j4 + 1] + bias[col + 1];
            o.z = acc[i][j4 + 2] + bias[col + 2];
            o.w = acc[i][j4 + 3] + bias[col + 3];
            if (RESID) {
                float4 rv = *reinterpret_cast<const float4*>(resid + (size_t)row * Ndim + col);
                o.x += rv.x; o.y += rv.y; o.z += rv.z; o.w += rv.w;
            }
            *reinterpret_cast<float4*>(out + (size_t)row * Ndim + col) = o;
        }
    }
}

// ---------------------------------------------------------------------------
// Attention: per (group g, 64-row q-tile). Flat-view heads (no transpose):
//   q_g[l2][d2] = qbuf[g*L*64 + l2*64 + d2].  scale = 0.5.
// Pass 1: online row max/sum over key chunks of 64.
// Pass 2: recompute scores, write normalized attention, accumulate PV.
// ---------------------------------------------------------------------------
__global__ __launch_bounds__(256) void attn_kernel(
    const float* __restrict__ qbuf, const float* __restrict__ kbuf,
    const float* __restrict__ vbuf, float* __restrict__ attn,
    float* __restrict__ ctx)
{
    __shared__ float qs[64][65];
    __shared__ float ks[64][65];
    __shared__ float vs[64][65];
    __shared__ float ps[64][65];

    const int g  = blockIdx.x;            // 0..31
    const int r0 = blockIdx.y * 64;       // q-row tile base
    const int t  = threadIdx.x;
    const int tr = t >> 4, tc = t & 15;

    const float* qg = qbuf + (size_t)g * Lseq * DPH;
    const float* kg = kbuf + (size_t)g * Lseq * DPH;
    const float* vg = vbuf + (size_t)g * Lseq * DPH;

    // load q tile (64x64 floats = 1024 float4, 4 per thread)
#pragma unroll
    for (int it = 0; it < 4; ++it) {
        int id  = t + it * 256;
        int row = id >> 4;
        int c4  = (id & 15) * 4;
        float4 v4 = *reinterpret_cast<const float4*>(qg + (size_t)(r0 + row) * DPH + c4);
        qs[row][c4 + 0] = v4.x; qs[row][c4 + 1] = v4.y;
        qs[row][c4 + 2] = v4.z; qs[row][c4 + 3] = v4.w;
    }

    float m[4], l[4];
#pragma unroll
    for (int i = 0; i < 4; ++i) { m[i] = -1e30f; l[i] = 0.f; }

#define SCORE_TILE(sarr)                                               \
    {                                                                  \
        _Pragma("unroll")                                              \
        for (int i = 0; i < 4; ++i)                                    \
            for (int j = 0; j < 4; ++j) sarr[i][j] = 0.f;              \
        _Pragma("unroll 8")                                            \
        for (int kk = 0; kk < 64; ++kk) {                              \
            float a[4], b[4];                                          \
            _Pragma("unroll")                                          \
            for (int i = 0; i < 4; ++i) a[i] = qs[tr * 4 + i][kk];     \
            _Pragma("unroll")                                          \
            for (int j = 0; j < 4; ++j) b[j] = ks[tc * 4 + j][kk];     \
            _Pragma("unroll")                                          \
            for (int i = 0; i < 4; ++i)                                \
                _Pragma("unroll")                                      \
                for (int j = 0; j < 4; ++j)                            \
                    sarr[i][j] = fmaf(a[i], b[j], sarr[i][j]);         \
        }                                                              \
        _Pragma("unroll")                                              \
        for (int i = 0; i < 4; ++i)                                    \
            for (int j = 0; j < 4; ++j) sarr[i][j] *= 0.5f;            \
    }

    // ---- pass 1: softmax stats ----
    for (int jc = 0; jc < Lseq / 64; ++jc) {
        __syncthreads();
#pragma unroll
        for (int it = 0; it < 4; ++it) {
            int id  = t + it * 256;
            int row = id >> 4;
            int c4  = (id & 15) * 4;
            float4 v4 = *reinterpret_cast<const float4*>(kg + (size_t)(jc * 64 + row) * DPH + c4);
            ks[row][c4 + 0] = v4.x; ks[row][c4 + 1] = v4.y;
            ks[row][c4 + 2] = v4.z; ks[row][c4 + 3] = v4.w;
        }
        __syncthreads();

        float s[4][4];
        SCORE_TILE(s);

#pragma unroll
        for (int i = 0; i < 4; ++i) {
            float cm = fmaxf(fmaxf(s[i][0], s[i][1]), fmaxf(s[i][2], s[i][3]));
            for (int off = 1; off < 16; off <<= 1) cm = fmaxf(cm, __shfl_xor(cm, off));
            float mn = fmaxf(m[i], cm);
            float se = 0.f;
#pragma unroll
            for (int j = 0; j < 4; ++j) se += __expf(s[i][j] - mn);
            for (int off = 1; off < 16; off <<= 1) se += __shfl_xor(se, off);
            l[i] = l[i] * __expf(m[i] - mn) + se;
            m[i] = mn;
        }
    }

    float invl[4];
#pragma unroll
    for (int i = 0; i < 4; ++i) invl[i] = 1.f / l[i];

    float cacc[4][4] = {};

    // ---- pass 2: attention write + PV ----
    for (int jc = 0; jc < Lseq / 64; ++jc) {
        __syncthreads();
#pragma unroll
        for (int it = 0; it < 4; ++it) {
            int id  = t + it * 256;
            int row = id >> 4;
            int c4  = (id & 15) * 4;
            float4 k4 = *reinterpret_cast<const float4*>(kg + (size_t)(jc * 64 + row) * DPH + c4);
            ks[row][c4 + 0] = k4.x; ks[row][c4 + 1] = k4.y;
            ks[row][c4 + 2] = k4.z; ks[row][c4 + 3] = k4.w;
            float4 v4 = *reinterpret_cast<const float4*>(vg + (size_t)(jc * 64 + row) * DPH + c4);
            vs[row][c4 + 0] = v4.x; vs[row][c4 + 1] = v4.y;
            vs[row][c4 + 2] = v4.z; vs[row][c4 + 3] = v4.w;
        }
        __syncthreads();

        float s[4][4];
        SCORE_TILE(s);

#pragma unroll
        for (int i = 0; i < 4; ++i) {
            float4 p4;
            p4.x = __expf(s[i][0] - m[i]) * invl[i];
            p4.y = __expf(s[i][1] - m[i]) * invl[i];
            p4.z = __expf(s[i][2] - m[i]) * invl[i];
            p4.w = __expf(s[i][3] - m[i]) * invl[i];
            *reinterpret_cast<float4*>(attn + (size_t)g * Lseq * Lseq
                                       + (size_t)(r0 + tr * 4 + i) * Lseq
                                       + jc * 64 + tc * 4) = p4;
            ps[tr * 4 + i][tc * 4 + 0] = p4.x;
            ps[tr * 4 + i][tc * 4 + 1] = p4.y;
            ps[tr * 4 + i][tc * 4 + 2] = p4.z;
            ps[tr * 4 + i][tc * 4 + 3] = p4.w;
        }
        __syncthreads();

#pragma unroll 8
        for (int j = 0; j < 64; ++j) {
            float pa[4], vv[4];
#pragma unroll
            for (int i = 0; i < 4; ++i) pa[i] = ps[tr * 4 + i][j];
#pragma unroll
            for (int d = 0; d < 4; ++d) vv[d] = vs[j][tc * 4 + d];
#pragma unroll
            for (int i = 0; i < 4; ++i)
#pragma unroll
                for (int d = 0; d < 4; ++d)
                    cacc[i][d] = fmaf(pa[i], vv[d], cacc[i][d]);
        }
    }

    // write context (flat view back to (B,L,D))
#pragma unroll
    for (int i = 0; i < 4; ++i) {
        float4 o; o.x = cacc[i][0]; o.y = cacc[i][1]; o.z = cacc[i][2]; o.w = cacc[i][3];
        *reinterpret_cast<float4*>(ctx + (size_t)g * Lseq * DPH
                                   + (size_t)(r0 + tr * 4 + i) * DPH + tc * 4) = o;
    }
#undef SCORE_TILE
}

// ---------------------------------------------------------------------------
// LayerNorm over D=1024, one block per row, in-place on d_out.
// ---------------------------------------------------------------------------
__global__ __launch_bounds__(256) void ln_kernel(
    float* __restrict__ x, const float* __restrict__ gamma,
    const float* __restrict__ beta, float* __restrict__ out)
{
    const int row = blockIdx.x;
    const int t   = threadIdx.x;
    const int c   = t * 4;

    float4 v = *reinterpret_cast<const float4*>(x + (size_t)row * Dmodel + c);
    float s  = v.x + v.y + v.z + v.w;
    float s2 = v.x * v.x + v.y * v.y + v.z * v.z + v.w * v.w;

    for (int off = 1; off < 64; off <<= 1) {
        s  += __shfl_xor(s, off);
        s2 += __shfl_xor(s2, off);
    }
    __shared__ float ssum[4], ssum2[4];
    int wid = t >> 6;
    if ((t & 63) == 0) { ssum[wid] = s; ssum2[wid] = s2; }
    __syncthreads();
    s  = ssum[0] + ssum[1] + ssum[2] + ssum[3];
    s2 = ssum2[0] + ssum2[1] + ssum2[2] + ssum2[3];

    float mean = s * (1.f / Dmodel);
    float var  = s2 * (1.f / Dmodel) - mean * mean;
    float rstd = rsqrtf(var + EPS_LN);

    float4 gv = *reinterpret_cast<const float4*>(gamma + c);
    float4 bv = *reinterpret_cast<const float4*>(beta + c);
    float4 o;
    o.x = (v.x - mean) * rstd * gv.x + bv.x;
    o.y = (v.y - mean) * rstd * gv.y + bv.y;
    o.z = (v.z - mean) * rstd * gv.z + bv.z;
    o.w = (v.w - mean) * rstd * gv.w + bv.w;
    *reinterpret_cast<float4*>(out + (size_t)row * Dmodel + c) = o;
}

// ---------------------------------------------------------------------------
extern "C" void kernel_launch(void* const* d_in, const int* in_sizes, int n_in,
                              void* d_out, int out_size, void* d_ws, size_t ws_size,
                              hipStream_t stream)
{
    const float* key   = (const float*)d_in[0];
    const float* value = (const float*)d_in[1];
    const float* query = (const float*)d_in[2];
    const float* Wq    = (const float*)d_in[3];
    const float* bq    = (const float*)d_in[4];
    const float* Wk    = (const float*)d_in[5];
    const float* bk    = (const float*)d_in[6];
    const float* Wv    = (const float*)d_in[7];
    const float* bv    = (const float*)d_in[8];
    const float* Wo    = (const float*)d_in[9];
    const float* bo    = (const float*)d_in[10];
    const float* gamma = (const float*)d_in[11];
    const float* beta  = (const float*)d_in[12];

    float* out  = (float*)d_out;
    float* attn = out + (size_t)MROWS * Dmodel;         // output 1 region

    float* ws   = (float*)d_ws;
    float* qbuf = ws;
    float* kbuf = ws + (size_t)1 * MROWS * Dmodel;
    float* vbuf = ws + (size_t)2 * MROWS * Dmodel;
    float* ctxb = ws + (size_t)3 * MROWS * Dmodel;

    dim3 gg(Dmodel / 128, MROWS / 128);   // (8, 32)
    dim3 gb(256);

    hipLaunchKernelGGL((gemm_bias<false>), gg, gb, 0, stream, query, Wq, bq, nullptr, qbuf, Dmodel, Dmodel);
    hipLaunchKernelGGL((gemm_bias<false>), gg, gb, 0, stream, key,   Wk, bk, nullptr, kbuf, Dmodel, Dmodel);
    hipLaunchKernelGGL((gemm_bias<false>), gg, gb, 0, stream, value, Wv, bv, nullptr, vbuf, Dmodel, Dmodel);

    hipLaunchKernelGGL(attn_kernel, dim3(NGRP, Lseq / 64), gb, 0, stream,
                       qbuf, kbuf, vbuf, attn, ctxb);

    hipLaunchKernelGGL((gemm_bias<true>), gg, gb, 0, stream, ctxb, Wo, bo, query, out, Dmodel, Dmodel);
    hipLaunchKernelGGL(ln_kernel, dim3(MROWS), gb, 0, stream, out, gamma, beta, out);
}

// Round 3
// 432.108 us; speedup vs baseline: 4.3626x; 4.3626x over previous
//
#include <hip/hip_runtime.h>
#include <cstddef>

#define Lseq   2048
#define Dmodel 1024
#define NGRP   32          // B*H
#define MROWS  4096        // B*L
#define EPS_LN 1e-5f

typedef short  s16x8 __attribute__((ext_vector_type(8)));
typedef float  f32x4 __attribute__((ext_vector_type(4)));
typedef unsigned short ushort_t;

__device__ __forceinline__ ushort_t f2bf(float f) {
    union { float f; unsigned u; } v; v.f = f;
    unsigned r = v.u + 0x7FFFu + ((v.u >> 16) & 1u);   // round-to-nearest-even
    return (ushort_t)(r >> 16);
}

// ---------------------------------------------------------------------------
// bf16-MFMA GEMM: out[M,N] = X[M,1024] @ W[N,1024]^T + bias (+resid)
// A source either fp32 (converted during staging) or bf16 (ushort).
// Tile 128x128, BK=32, 256 threads (4 waves, 2x2), 16x16x32 MFMA.
// ---------------------------------------------------------------------------
template<bool A_IS_F32, bool OUT_BF16>
__global__ __launch_bounds__(256) void gemm_mfma(
    const void* __restrict__ Xv, const float* __restrict__ W,
    const float* __restrict__ bias, const float* __restrict__ resid,
    void* __restrict__ outv)
{
    __shared__ ushort_t As[128][40];   // row stride 80B (16B aligned, bank-spread)
    __shared__ ushort_t Bs[128][40];

    const int t  = threadIdx.x;
    const int m0 = blockIdx.y * 128;
    const int n0 = blockIdx.x * 128;
    const int w  = t >> 6;
    const int l  = t & 63;
    const int lr = l & 15;
    const int lg = l >> 4;
    const int wm = w >> 1, wn = w & 1;

    const float*    Xf = (const float*)Xv;
    const ushort_t* Xb = (const ushort_t*)Xv;

    f32x4 acc[4][4] = {};

    for (int k0 = 0; k0 < 1024; k0 += 32) {
#pragma unroll
        for (int it = 0; it < 2; ++it) {
            int s   = t * 2 + it;          // 0..511
            int row = s >> 2;              // 0..127
            int sub = (s & 3) * 8;         // 0,8,16,24
            // A tile
            s16x8 av;
            if (A_IS_F32) {
                const float* p = Xf + (size_t)(m0 + row) * 1024 + k0 + sub;
                float4 x0 = *reinterpret_cast<const float4*>(p);
                float4 x1 = *reinterpret_cast<const float4*>(p + 4);
                av[0]=f2bf(x0.x); av[1]=f2bf(x0.y); av[2]=f2bf(x0.z); av[3]=f2bf(x0.w);
                av[4]=f2bf(x1.x); av[5]=f2bf(x1.y); av[6]=f2bf(x1.z); av[7]=f2bf(x1.w);
            } else {
                av = *reinterpret_cast<const s16x8*>(Xb + (size_t)(m0 + row) * 1024 + k0 + sub);
            }
            *reinterpret_cast<s16x8*>(&As[row][sub]) = av;
            // B tile (weights, always fp32)
            const float* q = W + (size_t)(n0 + row) * 1024 + k0 + sub;
            float4 w0 = *reinterpret_cast<const float4*>(q);
            float4 w1 = *reinterpret_cast<const float4*>(q + 4);
            s16x8 bv;
            bv[0]=f2bf(w0.x); bv[1]=f2bf(w0.y); bv[2]=f2bf(w0.z); bv[3]=f2bf(w0.w);
            bv[4]=f2bf(w1.x); bv[5]=f2bf(w1.y); bv[6]=f2bf(w1.z); bv[7]=f2bf(w1.w);
            *reinterpret_cast<s16x8*>(&Bs[row][sub]) = bv;
        }
        __syncthreads();

        s16x8 af[4], bf[4];
#pragma unroll
        for (int mi = 0; mi < 4; ++mi)
            af[mi] = *reinterpret_cast<const s16x8*>(&As[wm*64 + mi*16 + lr][lg*8]);
#pragma unroll
        for (int ni = 0; ni < 4; ++ni)
            bf[ni] = *reinterpret_cast<const s16x8*>(&Bs[wn*64 + ni*16 + lr][lg*8]);
#pragma unroll
        for (int mi = 0; mi < 4; ++mi)
#pragma unroll
            for (int ni = 0; ni < 4; ++ni)
                acc[mi][ni] = __builtin_amdgcn_mfma_f32_16x16x32_bf16(af[mi], bf[ni], acc[mi][ni], 0, 0, 0);
        __syncthreads();
    }

    // epilogue
#pragma unroll
    for (int mi = 0; mi < 4; ++mi)
#pragma unroll
        for (int ni = 0; ni < 4; ++ni)
#pragma unroll
            for (int r = 0; r < 4; ++r) {
                int row = m0 + wm*64 + mi*16 + lg*4 + r;
                int col = n0 + wn*64 + ni*16 + lr;
                float v = acc[mi][ni][r] + bias[col];
                if (OUT_BF16) {
                    ((ushort_t*)outv)[(size_t)row * 1024 + col] = f2bf(v);
                } else {
                    v += resid[(size_t)row * 1024 + col];
                    ((float*)outv)[(size_t)row * 1024 + col] = v;
                }
            }
}

// ---------------------------------------------------------------------------
// V transpose: vb[32][2048][64] -> vt[32][64][2048]  (bf16, flat-view groups)
// ---------------------------------------------------------------------------
__global__ __launch_bounds__(256) void transpose_v(
    const ushort_t* __restrict__ vb, ushort_t* __restrict__ vt)
{
    __shared__ ushort_t tile[64][72];
    const int g  = blockIdx.x;
    const int lt = blockIdx.y;
    const int t  = threadIdx.x;
#pragma unroll
    for (int it = 0; it < 2; ++it) {
        int s = t * 2 + it, row = s >> 3, sub = (s & 7) * 8;
        *reinterpret_cast<s16x8*>(&tile[row][sub]) =
            *reinterpret_cast<const s16x8*>(vb + ((size_t)(g*2048 + lt*64 + row))*64 + sub);
    }
    __syncthreads();
#pragma unroll
    for (int it = 0; it < 2; ++it) {
        int s = t * 2 + it, drow = s >> 3, sub = (s & 7) * 8;
        s16x8 o;
#pragma unroll
        for (int j = 0; j < 8; ++j) o[j] = (short)tile[sub + j][drow];
        *reinterpret_cast<s16x8*>(vt + ((size_t)(g*64 + drow))*2048 + lt*64 + sub) = o;
    }
}

// ---------------------------------------------------------------------------
// Attention: block = (g, 64 q-rows), 4 waves x 16 rows.
// Pass 1: scores->exp->rowsum + unnormalized PV (MFMA). Pass 2: recompute,
// write normalized probs. No max-subtraction (scores bounded ~|10|).
// ALL indexing is flat-view: group g rows are contiguous 64-elem chunks.
// ---------------------------------------------------------------------------
__global__ __launch_bounds__(256) void attn_mfma(
    const ushort_t* __restrict__ qb, const ushort_t* __restrict__ kb,
    const ushort_t* __restrict__ vt, float* __restrict__ attn,
    ushort_t* __restrict__ ctxb)
{
    __shared__ ushort_t Ks[64][72];   // row stride 144B
    __shared__ ushort_t Vs[64][72];   // V^T chunk: [dim][key]
    __shared__ ushort_t Ps[64][72];   // P chunk (bf16)

    const int g  = blockIdx.x;
    const int r0 = blockIdx.y * 64;
    const int t  = threadIdx.x;
    const int w  = t >> 6;
    const int l  = t & 63;
    const int lr = l & 15;
    const int lg = l >> 4;

    // Q fragments for this wave's 16 rows (held in registers)
    s16x8 qf0, qf1;
    {
        const ushort_t* qrow = qb + ((size_t)(g*2048 + r0 + w*16 + lr)) * 64;
        qf0 = *reinterpret_cast<const s16x8*>(qrow + lg*8);
        qf1 = *reinterpret_cast<const s16x8*>(qrow + 32 + lg*8);
    }

    float lsum[4] = {0.f, 0.f, 0.f, 0.f};
    f32x4 ctx[4] = {};

    for (int jc = 0; jc < 32; ++jc) {
        // stage K chunk [key][dim] and V^T chunk [dim][key]
#pragma unroll
        for (int it = 0; it < 2; ++it) {
            int s = t * 2 + it, row = s >> 3, sub = (s & 7) * 8;
            *reinterpret_cast<s16x8*>(&Ks[row][sub]) =
                *reinterpret_cast<const s16x8*>(kb + ((size_t)(g*2048 + jc*64 + row))*64 + sub);
            *reinterpret_cast<s16x8*>(&Vs[row][sub]) =
                *reinterpret_cast<const s16x8*>(vt + ((size_t)(g*64 + row))*2048 + jc*64 + sub);
        }
        __syncthreads();

        // QK^T (16 rows x 64 keys per wave) -> exp -> rowsum + Ps
#pragma unroll
        for (int jf = 0; jf < 4; ++jf) {
            s16x8 b0 = *reinterpret_cast<const s16x8*>(&Ks[jf*16 + lr][lg*8]);
            s16x8 b1 = *reinterpret_cast<const s16x8*>(&Ks[jf*16 + lr][32 + lg*8]);
            f32x4 s = {};
            s = __builtin_amdgcn_mfma_f32_16x16x32_bf16(qf0, b0, s, 0, 0, 0);
            s = __builtin_amdgcn_mfma_f32_16x16x32_bf16(qf1, b1, s, 0, 0, 0);
#pragma unroll
            for (int r = 0; r < 4; ++r) {
                float e = __expf(s[r] * 0.5f);
                lsum[r] += e;
                Ps[w*16 + lg*4 + r][jf*16 + lr] = f2bf(e);
            }
        }
        __syncthreads();   // Ps visible (cross-lane), Vs stable

        // PV: ctx[16 rows x 64 dims] += P(16x64) @ V(64x64)
#pragma unroll
        for (int kk = 0; kk < 2; ++kk) {
            s16x8 pa = *reinterpret_cast<const s16x8*>(&Ps[w*16 + lr][kk*32 + lg*8]);
#pragma unroll
            for (int ni = 0; ni < 4; ++ni) {
                s16x8 bv = *reinterpret_cast<const s16x8*>(&Vs[ni*16 + lr][kk*32 + lg*8]);
                ctx[ni] = __builtin_amdgcn_mfma_f32_16x16x32_bf16(pa, bv, ctx[ni], 0, 0, 0);
            }
        }
        __syncthreads();   // before restaging Ks/Vs
    }

    // finalize row sums (reduce across the 16 col-lanes of each group)
    float inv[4];
#pragma unroll
    for (int r = 0; r < 4; ++r) {
        float v = lsum[r];
        v += __shfl_xor(v, 1); v += __shfl_xor(v, 2);
        v += __shfl_xor(v, 4); v += __shfl_xor(v, 8);
        inv[r] = 1.f / v;
    }

    // write ctx (normalized) as bf16 — FLAT VIEW: ctx[g][l2][d2] lives at
    // g*L*64 + l2*64 + d2 (the reference reshape is a flat view, no head
    // transpose — round-2 bug was interleaving heads here).
#pragma unroll
    for (int ni = 0; ni < 4; ++ni)
#pragma unroll
        for (int r = 0; r < 4; ++r) {
            int l2 = r0 + w*16 + lg*4 + r;
            int d2 = ni*16 + lr;
            ctxb[(size_t)g*Lseq*64 + (size_t)l2*64 + d2] = f2bf(ctx[ni][r] * inv[r]);
        }

    // pass 2: recompute scores, write normalized attention probs (fp32)
    for (int jc = 0; jc < 32; ++jc) {
#pragma unroll
        for (int it = 0; it < 2; ++it) {
            int s = t * 2 + it, row = s >> 3, sub = (s & 7) * 8;
            *reinterpret_cast<s16x8*>(&Ks[row][sub]) =
                *reinterpret_cast<const s16x8*>(kb + ((size_t)(g*2048 + jc*64 + row))*64 + sub);
        }
        __syncthreads();
#pragma unroll
        for (int jf = 0; jf < 4; ++jf) {
            s16x8 b0 = *reinterpret_cast<const s16x8*>(&Ks[jf*16 + lr][lg*8]);
            s16x8 b1 = *reinterpret_cast<const s16x8*>(&Ks[jf*16 + lr][32 + lg*8]);
            f32x4 s = {};
            s = __builtin_amdgcn_mfma_f32_16x16x32_bf16(qf0, b0, s, 0, 0, 0);
            s = __builtin_amdgcn_mfma_f32_16x16x32_bf16(qf1, b1, s, 0, 0, 0);
#pragma unroll
            for (int r = 0; r < 4; ++r) {
                float p = __expf(s[r] * 0.5f) * inv[r];
                attn[(size_t)g*Lseq*Lseq + (size_t)(r0 + w*16 + lg*4 + r)*Lseq + jc*64 + jf*16 + lr] = p;
            }
        }
        __syncthreads();
    }
}

// ---------------------------------------------------------------------------
// LayerNorm over D=1024, one block per row, in-place.
// ---------------------------------------------------------------------------
__global__ __launch_bounds__(256) void ln_kernel(
    float* __restrict__ x, const float* __restrict__ gamma,
    const float* __restrict__ beta, float* __restrict__ out)
{
    const int row = blockIdx.x;
    const int t   = threadIdx.x;
    const int c   = t * 4;

    float4 v = *reinterpret_cast<const float4*>(x + (size_t)row * Dmodel + c);
    float s  = v.x + v.y + v.z + v.w;
    float s2 = v.x*v.x + v.y*v.y + v.z*v.z + v.w*v.w;
    for (int off = 1; off < 64; off <<= 1) {
        s  += __shfl_xor(s, off);
        s2 += __shfl_xor(s2, off);
    }
    __shared__ float ssum[4], ssum2[4];
    int wid = t >> 6;
    if ((t & 63) == 0) { ssum[wid] = s; ssum2[wid] = s2; }
    __syncthreads();
    s  = ssum[0] + ssum[1] + ssum[2] + ssum[3];
    s2 = ssum2[0] + ssum2[1] + ssum2[2] + ssum2[3];

    float mean = s * (1.f / Dmodel);
    float var  = s2 * (1.f / Dmodel) - mean * mean;
    float rstd = rsqrtf(var + EPS_LN);

    float4 gv = *reinterpret_cast<const float4*>(gamma + c);
    float4 bv = *reinterpret_cast<const float4*>(beta + c);
    float4 o;
    o.x = (v.x - mean) * rstd * gv.x + bv.x;
    o.y = (v.y - mean) * rstd * gv.y + bv.y;
    o.z = (v.z - mean) * rstd * gv.z + bv.z;
    o.w = (v.w - mean) * rstd * gv.w + bv.w;
    *reinterpret_cast<float4*>(out + (size_t)row * Dmodel + c) = o;
}

// ---------------------------------------------------------------------------
extern "C" void kernel_launch(void* const* d_in, const int* in_sizes, int n_in,
                              void* d_out, int out_size, void* d_ws, size_t ws_size,
                              hipStream_t stream)
{
    const float* key   = (const float*)d_in[0];
    const float* value = (const float*)d_in[1];
    const float* query = (const float*)d_in[2];
    const float* Wq    = (const float*)d_in[3];
    const float* bq    = (const float*)d_in[4];
    const float* Wk    = (const float*)d_in[5];
    const float* bk    = (const float*)d_in[6];
    const float* Wv    = (const float*)d_in[7];
    const float* bv    = (const float*)d_in[8];
    const float* Wo    = (const float*)d_in[9];
    const float* bo    = (const float*)d_in[10];
    const float* gamma = (const float*)d_in[11];
    const float* beta  = (const float*)d_in[12];

    float* out  = (float*)d_out;
    float* attn = out + (size_t)MROWS * Dmodel;

    ushort_t* ws   = (ushort_t*)d_ws;
    ushort_t* qb   = ws;                            // 4M bf16
    ushort_t* kb   = ws + (size_t)4*1024*1024;
    ushort_t* vb   = ws + (size_t)8*1024*1024;
    ushort_t* vt   = ws + (size_t)12*1024*1024;
    ushort_t* ctxb = ws + (size_t)16*1024*1024;

    dim3 gg(8, 32);     // N/128, M/128
    dim3 gb(256);

    gemm_mfma<true,  true ><<<gg, gb, 0, stream>>>(query, Wq, bq, nullptr, qb);
    gemm_mfma<true,  true ><<<gg, gb, 0, stream>>>(key,   Wk, bk, nullptr, kb);
    gemm_mfma<true,  true ><<<gg, gb, 0, stream>>>(value, Wv, bv, nullptr, vb);

    transpose_v<<<dim3(NGRP, Lseq/64), gb, 0, stream>>>(vb, vt);

    attn_mfma<<<dim3(NGRP, Lseq/64), gb, 0, stream>>>(qb, kb, vt, attn, ctxb);

    gemm_mfma<false, false><<<gg, gb, 0, stream>>>(ctxb, Wo, bo, query, out);

    ln_kernel<<<dim3(MROWS), gb, 0, stream>>>(out, gamma, beta, out);
}

// Round 4
// 385.298 us; speedup vs baseline: 4.8926x; 1.1215x over previous
//
#include <hip/hip_runtime.h>
#include <cstddef>
#include <cstdint>

#define Lseq   2048
#define Dmodel 1024
#define NGRP   32          // B*H
#define MROWS  4096        // B*L
#define EPS_LN 1e-5f

typedef short  s16x8 __attribute__((ext_vector_type(8)));
typedef float  f32x4 __attribute__((ext_vector_type(4)));
typedef unsigned short ushort_t;

__device__ __forceinline__ ushort_t f2bf(float f) {
    union { float f; unsigned u; } v; v.f = f;
    unsigned r = v.u + 0x7FFFu + ((v.u >> 16) & 1u);   // round-to-nearest-even
    return (ushort_t)(r >> 16);
}

// CK-idiom addrspace casts (uintptr round-trip; folded by InferAddressSpaces)
__device__ __forceinline__ void gld16(const ushort_t* g, ushort_t* lds) {
    __builtin_amdgcn_global_load_lds(
        (const __attribute__((address_space(1))) unsigned int*)(uintptr_t)g,
        (__attribute__((address_space(3))) unsigned int*)(uintptr_t)lds,
        16, 0, 0);
}

// ---------------------------------------------------------------------------
// Pre-convert fp32 -> bf16 for Q/K/V inputs and the 4 weight matrices.
// ---------------------------------------------------------------------------
struct CvtArgs {
    const float* src[7];
    ushort_t*    dst[7];
    int          n8[7];     // element count / 8
};

__global__ __launch_bounds__(256) void cvt_bf16(CvtArgs a)
{
    const int ti = blockIdx.y;
    const float* __restrict__ s = a.src[ti];
    ushort_t* __restrict__    d = a.dst[ti];
    const int n8 = a.n8[ti];
    for (int i = blockIdx.x * 256 + threadIdx.x; i < n8; i += gridDim.x * 256) {
        float4 x0 = reinterpret_cast<const float4*>(s)[i * 2];
        float4 x1 = reinterpret_cast<const float4*>(s)[i * 2 + 1];
        s16x8 o;
        o[0]=f2bf(x0.x); o[1]=f2bf(x0.y); o[2]=f2bf(x0.z); o[3]=f2bf(x0.w);
        o[4]=f2bf(x1.x); o[5]=f2bf(x1.y); o[6]=f2bf(x1.z); o[7]=f2bf(x1.w);
        reinterpret_cast<s16x8*>(d)[i] = o;
    }
}

// ---------------------------------------------------------------------------
// bf16 GEMM, m97 structure: out[M,N] = A[M,1024] @ W[N,1024]^T + bias (+resid)
// A,W pre-converted bf16. Tile 128x64, BK=32, 256 thr (4 waves 2x2),
// global_load_lds width-16 staging into linear LDS.
// ---------------------------------------------------------------------------
template<bool OUT_BF16>
__global__ __launch_bounds__(256) void gemm_async(
    const ushort_t* __restrict__ A, const ushort_t* __restrict__ W,
    const float* __restrict__ bias, const float* __restrict__ resid,
    void* __restrict__ outv)
{
    __shared__ ushort_t As[128 * 32];   // linear, row stride 32 elems (64 B)
    __shared__ ushort_t Bs[64 * 32];

    const int t  = threadIdx.x;
    const int m0 = blockIdx.y * 128;
    const int n0 = blockIdx.x * 64;
    const int w  = t >> 6;
    const int l  = t & 63;
    const int lr = l & 15;
    const int lg = l >> 4;
    const int wm = w >> 1, wn = w & 1;

    // per-lane global sources; wave-uniform LDS bases (HW adds lane*16B)
    const ushort_t* ga0 = A + (size_t)(m0 + w * 32 + (l >> 2)) * 1024 + (l & 3) * 8;
    const ushort_t* ga1 = ga0 + (size_t)16 * 1024;
    const ushort_t* gb0 = W + (size_t)(n0 + w * 16 + (l >> 2)) * 1024 + (l & 3) * 8;
    ushort_t* la0 = &As[(w * 32) * 32];
    ushort_t* la1 = &As[(w * 32 + 16) * 32];
    ushort_t* lb0 = &Bs[(w * 16) * 32];

    f32x4 acc[4][2] = {};

    for (int k0 = 0; k0 < 1024; k0 += 32) {
        gld16(ga0 + k0, la0);
        gld16(ga1 + k0, la1);
        gld16(gb0 + k0, lb0);
        __syncthreads();

        s16x8 af[4], bf[2];
#pragma unroll
        for (int mi = 0; mi < 4; ++mi)
            af[mi] = *reinterpret_cast<const s16x8*>(&As[(wm * 64 + mi * 16 + lr) * 32 + lg * 8]);
#pragma unroll
        for (int ni = 0; ni < 2; ++ni)
            bf[ni] = *reinterpret_cast<const s16x8*>(&Bs[(wn * 32 + ni * 16 + lr) * 32 + lg * 8]);
#pragma unroll
        for (int mi = 0; mi < 4; ++mi)
#pragma unroll
            for (int ni = 0; ni < 2; ++ni)
                acc[mi][ni] = __builtin_amdgcn_mfma_f32_16x16x32_bf16(af[mi], bf[ni], acc[mi][ni], 0, 0, 0);
        __syncthreads();
    }

#pragma unroll
    for (int mi = 0; mi < 4; ++mi)
#pragma unroll
        for (int ni = 0; ni < 2; ++ni)
#pragma unroll
            for (int r = 0; r < 4; ++r) {
                int row = m0 + wm * 64 + mi * 16 + lg * 4 + r;
                int col = n0 + wn * 32 + ni * 16 + lr;
                float v = acc[mi][ni][r] + bias[col];
                if (OUT_BF16) {
                    ((ushort_t*)outv)[(size_t)row * 1024 + col] = f2bf(v);
                } else {
                    v += resid[(size_t)row * 1024 + col];
                    ((float*)outv)[(size_t)row * 1024 + col] = v;
                }
            }
}

// ---------------------------------------------------------------------------
// V transpose: vb[32][2048][64] -> vt[32][64][2048]  (bf16, flat-view groups)
// ---------------------------------------------------------------------------
__global__ __launch_bounds__(256) void transpose_v(
    const ushort_t* __restrict__ vb, ushort_t* __restrict__ vt)
{
    __shared__ ushort_t tile[64][72];
    const int g  = blockIdx.x;
    const int lt = blockIdx.y;
    const int t  = threadIdx.x;
#pragma unroll
    for (int it = 0; it < 2; ++it) {
        int s = t * 2 + it, row = s >> 3, sub = (s & 7) * 8;
        *reinterpret_cast<s16x8*>(&tile[row][sub]) =
            *reinterpret_cast<const s16x8*>(vb + ((size_t)(g*2048 + lt*64 + row))*64 + sub);
    }
    __syncthreads();
#pragma unroll
    for (int it = 0; it < 2; ++it) {
        int s = t * 2 + it, drow = s >> 3, sub = (s & 7) * 8;
        s16x8 o;
#pragma unroll
        for (int j = 0; j < 8; ++j) o[j] = (short)tile[sub + j][drow];
        *reinterpret_cast<s16x8*>(vt + ((size_t)(g*64 + drow))*2048 + lt*64 + sub) = o;
    }
}

// ---------------------------------------------------------------------------
// attn_stats: row sums of exp(0.5*QK^T) -> invb (1/sum).  128 q-rows/block.
// ---------------------------------------------------------------------------
__global__ __launch_bounds__(256) void attn_stats(
    const ushort_t* __restrict__ qb, const ushort_t* __restrict__ kb,
    float* __restrict__ invb)
{
    __shared__ ushort_t Ks[64][72];

    const int g  = blockIdx.x;
    const int r0 = blockIdx.y * 128;
    const int t  = threadIdx.x;
    const int w  = t >> 6;
    const int l  = t & 63;
    const int lr = l & 15;
    const int lg = l >> 4;

    s16x8 qf[2][2];
#pragma unroll
    for (int rf = 0; rf < 2; ++rf) {
        const ushort_t* qrow = qb + ((size_t)(g*2048 + r0 + w*32 + rf*16 + lr)) * 64;
        qf[rf][0] = *reinterpret_cast<const s16x8*>(qrow + lg*8);
        qf[rf][1] = *reinterpret_cast<const s16x8*>(qrow + 32 + lg*8);
    }

    float lsum[2][4] = {};

    for (int jc = 0; jc < 32; ++jc) {
#pragma unroll
        for (int it = 0; it < 2; ++it) {
            int s = t * 2 + it, row = s >> 3, sub = (s & 7) * 8;
            *reinterpret_cast<s16x8*>(&Ks[row][sub]) =
                *reinterpret_cast<const s16x8*>(kb + ((size_t)(g*2048 + jc*64 + row))*64 + sub);
        }
        __syncthreads();
#pragma unroll
        for (int jf = 0; jf < 4; ++jf) {
            s16x8 b0 = *reinterpret_cast<const s16x8*>(&Ks[jf*16 + lr][lg*8]);
            s16x8 b1 = *reinterpret_cast<const s16x8*>(&Ks[jf*16 + lr][32 + lg*8]);
#pragma unroll
            for (int rf = 0; rf < 2; ++rf) {
                f32x4 sv = {};
                sv = __builtin_amdgcn_mfma_f32_16x16x32_bf16(qf[rf][0], b0, sv, 0, 0, 0);
                sv = __builtin_amdgcn_mfma_f32_16x16x32_bf16(qf[rf][1], b1, sv, 0, 0, 0);
#pragma unroll
                for (int r = 0; r < 4; ++r)
                    lsum[rf][r] += __expf(sv[r] * 0.5f);
            }
        }
        __syncthreads();
    }

#pragma unroll
    for (int rf = 0; rf < 2; ++rf)
#pragma unroll
        for (int r = 0; r < 4; ++r) {
            float v = lsum[rf][r];
            v += __shfl_xor(v, 1); v += __shfl_xor(v, 2);
            v += __shfl_xor(v, 4); v += __shfl_xor(v, 8);
            if (lr == 0)
                invb[(size_t)g*2048 + r0 + w*32 + rf*16 + lg*4 + r] = 1.f / v;
        }
}

// ---------------------------------------------------------------------------
// attn_main: single pass. QK^T -> exp -> write normalized attention (fp32)
// and Ps (bf16) -> PV MFMA. inv preloaded from attn_stats.
// ---------------------------------------------------------------------------
__global__ __launch_bounds__(256) void attn_main(
    const ushort_t* __restrict__ qb, const ushort_t* __restrict__ kb,
    const ushort_t* __restrict__ vt, const float* __restrict__ invb,
    float* __restrict__ attn, ushort_t* __restrict__ ctxb)
{
    __shared__ ushort_t Ks[64][72];
    __shared__ ushort_t Vs[64][72];
    __shared__ ushort_t Ps[64][72];

    const int g  = blockIdx.x;
    const int r0 = blockIdx.y * 64;
    const int t  = threadIdx.x;
    const int w  = t >> 6;
    const int l  = t & 63;
    const int lr = l & 15;
    const int lg = l >> 4;

    s16x8 qf0, qf1;
    {
        const ushort_t* qrow = qb + ((size_t)(g*2048 + r0 + w*16 + lr)) * 64;
        qf0 = *reinterpret_cast<const s16x8*>(qrow + lg*8);
        qf1 = *reinterpret_cast<const s16x8*>(qrow + 32 + lg*8);
    }

    float inv[4];
#pragma unroll
    for (int r = 0; r < 4; ++r)
        inv[r] = invb[(size_t)g*2048 + r0 + w*16 + lg*4 + r];

    f32x4 ctx[4] = {};

    for (int jc = 0; jc < 32; ++jc) {
#pragma unroll
        for (int it = 0; it < 2; ++it) {
            int s = t * 2 + it, row = s >> 3, sub = (s & 7) * 8;
            *reinterpret_cast<s16x8*>(&Ks[row][sub]) =
                *reinterpret_cast<const s16x8*>(kb + ((size_t)(g*2048 + jc*64 + row))*64 + sub);
            *reinterpret_cast<s16x8*>(&Vs[row][sub]) =
                *reinterpret_cast<const s16x8*>(vt + ((size_t)(g*64 + row))*2048 + jc*64 + sub);
        }
        __syncthreads();

#pragma unroll
        for (int jf = 0; jf < 4; ++jf) {
            s16x8 b0 = *reinterpret_cast<const s16x8*>(&Ks[jf*16 + lr][lg*8]);
            s16x8 b1 = *reinterpret_cast<const s16x8*>(&Ks[jf*16 + lr][32 + lg*8]);
            f32x4 s = {};
            s = __builtin_amdgcn_mfma_f32_16x16x32_bf16(qf0, b0, s, 0, 0, 0);
            s = __builtin_amdgcn_mfma_f32_16x16x32_bf16(qf1, b1, s, 0, 0, 0);
#pragma unroll
            for (int r = 0; r < 4; ++r) {
                float e = __expf(s[r] * 0.5f);
                attn[(size_t)g*Lseq*Lseq + (size_t)(r0 + w*16 + lg*4 + r)*Lseq
                     + jc*64 + jf*16 + lr] = e * inv[r];
                Ps[w*16 + lg*4 + r][jf*16 + lr] = f2bf(e);
            }
        }
        __syncthreads();   // Ps cross-lane visible, Vs stable

#pragma unroll
        for (int kk = 0; kk < 2; ++kk) {
            s16x8 pa = *reinterpret_cast<const s16x8*>(&Ps[w*16 + lr][kk*32 + lg*8]);
#pragma unroll
            for (int ni = 0; ni < 4; ++ni) {
                s16x8 bv = *reinterpret_cast<const s16x8*>(&Vs[ni*16 + lr][kk*32 + lg*8]);
                ctx[ni] = __builtin_amdgcn_mfma_f32_16x16x32_bf16(pa, bv, ctx[ni], 0, 0, 0);
            }
        }
        __syncthreads();   // before restaging Ks/Vs
    }

    // ctx write — FLAT VIEW: g*L*64 + l2*64 + d2
#pragma unroll
    for (int ni = 0; ni < 4; ++ni)
#pragma unroll
        for (int r = 0; r < 4; ++r) {
            int l2 = r0 + w*16 + lg*4 + r;
            int d2 = ni*16 + lr;
            ctxb[(size_t)g*Lseq*64 + (size_t)l2*64 + d2] = f2bf(ctx[ni][r] * inv[r]);
        }
}

// ---------------------------------------------------------------------------
// LayerNorm over D=1024, one block per row, in-place.
// ---------------------------------------------------------------------------
__global__ __launch_bounds__(256) void ln_kernel(
    float* __restrict__ x, const float* __restrict__ gamma,
    const float* __restrict__ beta, float* __restrict__ out)
{
    const int row = blockIdx.x;
    const int t   = threadIdx.x;
    const int c   = t * 4;

    float4 v = *reinterpret_cast<const float4*>(x + (size_t)row * Dmodel + c);
    float s  = v.x + v.y + v.z + v.w;
    float s2 = v.x*v.x + v.y*v.y + v.z*v.z + v.w*v.w;
    for (int off = 1; off < 64; off <<= 1) {
        s  += __shfl_xor(s, off);
        s2 += __shfl_xor(s2, off);
    }
    __shared__ float ssum[4], ssum2[4];
    int wid = t >> 6;
    if ((t & 63) == 0) { ssum[wid] = s; ssum2[wid] = s2; }
    __syncthreads();
    s  = ssum[0] + ssum[1] + ssum[2] + ssum[3];
    s2 = ssum2[0] + ssum2[1] + ssum2[2] + ssum2[3];

    float mean = s * (1.f / Dmodel);
    float var  = s2 * (1.f / Dmodel) - mean * mean;
    float rstd = rsqrtf(var + EPS_LN);

    float4 gv = *reinterpret_cast<const float4*>(gamma + c);
    float4 bv = *reinterpret_cast<const float4*>(beta + c);
    float4 o;
    o.x = (v.x - mean) * rstd * gv.x + bv.x;
    o.y = (v.y - mean) * rstd * gv.y + bv.y;
    o.z = (v.z - mean) * rstd * gv.z + bv.z;
    o.w = (v.w - mean) * rstd * gv.w + bv.w;
    *reinterpret_cast<float4*>(out + (size_t)row * Dmodel + c) = o;
}

// ---------------------------------------------------------------------------
extern "C" void kernel_launch(void* const* d_in, const int* in_sizes, int n_in,
                              void* d_out, int out_size, void* d_ws, size_t ws_size,
                              hipStream_t stream)
{
    const float* key   = (const float*)d_in[0];
    const float* value = (const float*)d_in[1];
    const float* query = (const float*)d_in[2];
    const float* Wq    = (const float*)d_in[3];
    const float* bq    = (const float*)d_in[4];
    const float* Wk    = (const float*)d_in[5];
    const float* bk    = (const float*)d_in[6];
    const float* Wv    = (const float*)d_in[7];
    const float* bv    = (const float*)d_in[8];
    const float* Wo    = (const float*)d_in[9];
    const float* bo    = (const float*)d_in[10];
    const float* gamma = (const float*)d_in[11];
    const float* beta  = (const float*)d_in[12];

    float* out  = (float*)d_out;
    float* attn = out + (size_t)MROWS * Dmodel;

    const size_t M1 = 1024 * 1024;
    ushort_t* ws   = (ushort_t*)d_ws;
    ushort_t* qb   = ws;                 // 4M
    ushort_t* kb   = ws + 4  * M1;       // 4M
    ushort_t* vb   = ws + 8  * M1;       // 4M
    ushort_t* vt   = ws + 12 * M1;       // 4M
    ushort_t* qx   = ws + 16 * M1;       // 4M (reused as ctxb after Q-GEMM)
    ushort_t* kx   = ws + 20 * M1;       // 4M (tail reused as invb after K-GEMM)
    ushort_t* vx   = ws + 24 * M1;       // 4M
    ushort_t* wqx  = ws + 28 * M1;       // 1M
    ushort_t* wkx  = ws + 29 * M1;       // 1M
    ushort_t* wvx  = ws + 30 * M1;       // 1M
    ushort_t* wox  = ws + 31 * M1;       // 1M  -> total 64 MB
    ushort_t* ctxb = qx;
    float*    invb = (float*)kx;

    // 1. convert everything to bf16
    CvtArgs ca;
    ca.src[0]=query; ca.dst[0]=qx;  ca.n8[0]=(int)(4*M1/8);
    ca.src[1]=key;   ca.dst[1]=kx;  ca.n8[1]=(int)(4*M1/8);
    ca.src[2]=value; ca.dst[2]=vx;  ca.n8[2]=(int)(4*M1/8);
    ca.src[3]=Wq;    ca.dst[3]=wqx; ca.n8[3]=(int)(M1/8);
    ca.src[4]=Wk;    ca.dst[4]=wkx; ca.n8[4]=(int)(M1/8);
    ca.src[5]=Wv;    ca.dst[5]=wvx; ca.n8[5]=(int)(M1/8);
    ca.src[6]=Wo;    ca.dst[6]=wox; ca.n8[6]=(int)(M1/8);
    cvt_bf16<<<dim3(512, 7), 256, 0, stream>>>(ca);

    dim3 gg(Dmodel / 64, MROWS / 128);   // (16, 32) = 512 blocks
    dim3 gb(256);

    // 2-4. projections
    gemm_async<true ><<<gg, gb, 0, stream>>>(qx, wqx, bq, nullptr, qb);
    gemm_async<true ><<<gg, gb, 0, stream>>>(kx, wkx, bk, nullptr, kb);
    gemm_async<true ><<<gg, gb, 0, stream>>>(vx, wvx, bv, nullptr, vb);

    // 5. V transpose
    transpose_v<<<dim3(NGRP, Lseq/64), gb, 0, stream>>>(vb, vt);

    // 6. softmax denominators
    attn_stats<<<dim3(NGRP, Lseq/128), gb, 0, stream>>>(qb, kb, invb);

    // 7. attention write + PV in one pass
    attn_main<<<dim3(NGRP, Lseq/64), gb, 0, stream>>>(qb, kb, vt, invb, attn, ctxb);

    // 8. output projection + residual
    gemm_async<false><<<gg, gb, 0, stream>>>(ctxb, wox, bo, query, out);

    // 9. LayerNorm
    ln_kernel<<<dim3(MROWS), gb, 0, stream>>>(out, gamma, beta, out);
}

// Round 5
// 335.168 us; speedup vs baseline: 5.6244x; 1.1496x over previous
//
#include <hip/hip_runtime.h>
#include <cstddef>
#include <cstdint>

#define Lseq   2048
#define Dmodel 1024
#define NGRP   32          // B*H
#define MROWS  4096        // B*L
#define EPS_LN 1e-5f

typedef short  s16x8 __attribute__((ext_vector_type(8)));
typedef float  f32x4 __attribute__((ext_vector_type(4)));
typedef unsigned short ushort_t;

__device__ __forceinline__ ushort_t f2bf(float f) {
    union { float f; unsigned u; } v; v.f = f;
    unsigned r = v.u + 0x7FFFu + ((v.u >> 16) & 1u);   // round-to-nearest-even
    return (ushort_t)(r >> 16);
}

// CK-idiom addrspace casts (uintptr round-trip; folded by InferAddressSpaces)
__device__ __forceinline__ void gld16(const ushort_t* g, ushort_t* lds) {
    __builtin_amdgcn_global_load_lds(
        (const __attribute__((address_space(1))) unsigned int*)(uintptr_t)g,
        (__attribute__((address_space(3))) unsigned int*)(uintptr_t)lds,
        16, 0, 0);
}

// ---------------------------------------------------------------------------
// Pre-convert fp32 -> bf16 for Q/K/V inputs and the 4 weight matrices.
// ---------------------------------------------------------------------------
struct CvtArgs {
    const float* src[7];
    ushort_t*    dst[7];
    int          n8[7];
};

__global__ __launch_bounds__(256) void cvt_bf16(CvtArgs a)
{
    const int ti = blockIdx.y;
    const float* __restrict__ s = a.src[ti];
    ushort_t* __restrict__    d = a.dst[ti];
    const int n8 = a.n8[ti];
    for (int i = blockIdx.x * 256 + threadIdx.x; i < n8; i += gridDim.x * 256) {
        float4 x0 = reinterpret_cast<const float4*>(s)[i * 2];
        float4 x1 = reinterpret_cast<const float4*>(s)[i * 2 + 1];
        s16x8 o;
        o[0]=f2bf(x0.x); o[1]=f2bf(x0.y); o[2]=f2bf(x0.z); o[3]=f2bf(x0.w);
        o[4]=f2bf(x1.x); o[5]=f2bf(x1.y); o[6]=f2bf(x1.z); o[7]=f2bf(x1.w);
        reinterpret_cast<s16x8*>(d)[i] = o;
    }
}

// ---------------------------------------------------------------------------
// Shared GEMM body (m97 structure): out[M,N] = A[M,1024] @ W[N,1024]^T + bias
// Tile 128x64, BK=32, 256 thr (4 waves 2x2), global_load_lds width-16.
// ---------------------------------------------------------------------------
template<bool OUT_BF16>
__device__ __forceinline__ void gemm_body(
    const ushort_t* __restrict__ A, const ushort_t* __restrict__ W,
    const float* __restrict__ bias, const float* __restrict__ resid,
    void* __restrict__ outv, ushort_t* As, ushort_t* Bs)
{
    const int t  = threadIdx.x;
    const int m0 = blockIdx.y * 128;
    const int n0 = blockIdx.x * 64;
    const int w  = t >> 6;
    const int l  = t & 63;
    const int lr = l & 15;
    const int lg = l >> 4;
    const int wm = w >> 1, wn = w & 1;

    const ushort_t* ga0 = A + (size_t)(m0 + w * 32 + (l >> 2)) * 1024 + (l & 3) * 8;
    const ushort_t* ga1 = ga0 + (size_t)16 * 1024;
    const ushort_t* gb0 = W + (size_t)(n0 + w * 16 + (l >> 2)) * 1024 + (l & 3) * 8;
    ushort_t* la0 = &As[(w * 32) * 32];
    ushort_t* la1 = &As[(w * 32 + 16) * 32];
    ushort_t* lb0 = &Bs[(w * 16) * 32];

    f32x4 acc[4][2] = {};

    for (int k0 = 0; k0 < 1024; k0 += 32) {
        gld16(ga0 + k0, la0);
        gld16(ga1 + k0, la1);
        gld16(gb0 + k0, lb0);
        __syncthreads();

        s16x8 af[4], bf[2];
#pragma unroll
        for (int mi = 0; mi < 4; ++mi)
            af[mi] = *reinterpret_cast<const s16x8*>(&As[(wm * 64 + mi * 16 + lr) * 32 + lg * 8]);
#pragma unroll
        for (int ni = 0; ni < 2; ++ni)
            bf[ni] = *reinterpret_cast<const s16x8*>(&Bs[(wn * 32 + ni * 16 + lr) * 32 + lg * 8]);
#pragma unroll
        for (int mi = 0; mi < 4; ++mi)
#pragma unroll
            for (int ni = 0; ni < 2; ++ni)
                acc[mi][ni] = __builtin_amdgcn_mfma_f32_16x16x32_bf16(af[mi], bf[ni], acc[mi][ni], 0, 0, 0);
        __syncthreads();
    }

#pragma unroll
    for (int mi = 0; mi < 4; ++mi)
#pragma unroll
        for (int ni = 0; ni < 2; ++ni)
#pragma unroll
            for (int r = 0; r < 4; ++r) {
                int row = m0 + wm * 64 + mi * 16 + lg * 4 + r;
                int col = n0 + wn * 32 + ni * 16 + lr;
                float v = acc[mi][ni][r] + bias[col];
                if (OUT_BF16) {
                    ((ushort_t*)outv)[(size_t)row * 1024 + col] = f2bf(v);
                } else {
                    v += resid[(size_t)row * 1024 + col];
                    ((float*)outv)[(size_t)row * 1024 + col] = v;
                }
            }
}

struct QkvArgs {
    const ushort_t* A[3];
    const ushort_t* W[3];
    const float*    bias[3];
    ushort_t*       out[3];
};

__global__ __launch_bounds__(256) void gemm_qkv(QkvArgs a)
{
    __shared__ ushort_t As[128 * 32];
    __shared__ ushort_t Bs[64 * 32];
    const int z = blockIdx.z;
    gemm_body<true>(a.A[z], a.W[z], a.bias[z], nullptr, a.out[z], As, Bs);
}

__global__ __launch_bounds__(256) void gemm_o(
    const ushort_t* __restrict__ A, const ushort_t* __restrict__ W,
    const float* __restrict__ bias, const float* __restrict__ resid,
    float* __restrict__ out)
{
    __shared__ ushort_t As[128 * 32];
    __shared__ ushort_t Bs[64 * 32];
    gemm_body<false>(A, W, bias, resid, out, As, Bs);
}

// ---------------------------------------------------------------------------
// V transpose: vb[32][2048][64] -> vt[32][64][2048]  (bf16, flat-view groups)
// ---------------------------------------------------------------------------
__global__ __launch_bounds__(256) void transpose_v(
    const ushort_t* __restrict__ vb, ushort_t* __restrict__ vt)
{
    __shared__ ushort_t tile[64][72];
    const int g  = blockIdx.x;
    const int lt = blockIdx.y;
    const int t  = threadIdx.x;
#pragma unroll
    for (int it = 0; it < 2; ++it) {
        int s = t * 2 + it, row = s >> 3, sub = (s & 7) * 8;
        *reinterpret_cast<s16x8*>(&tile[row][sub]) =
            *reinterpret_cast<const s16x8*>(vb + ((size_t)(g*2048 + lt*64 + row))*64 + sub);
    }
    __syncthreads();
#pragma unroll
    for (int it = 0; it < 2; ++it) {
        int s = t * 2 + it, drow = s >> 3, sub = (s & 7) * 8;
        s16x8 o;
#pragma unroll
        for (int j = 0; j < 8; ++j) o[j] = (short)tile[sub + j][drow];
        *reinterpret_cast<s16x8*>(vt + ((size_t)(g*64 + drow))*2048 + lt*64 + sub) = o;
    }
}

// ---------------------------------------------------------------------------
// attn_stats: row sums of exp(0.5*QK^T) -> invb (1/sum).  128 q-rows/block.
// Double-buffered K staging, 1 barrier per 64-key chunk.
// ---------------------------------------------------------------------------
__global__ __launch_bounds__(256) void attn_stats(
    const ushort_t* __restrict__ qb, const ushort_t* __restrict__ kb,
    float* __restrict__ invb)
{
    __shared__ ushort_t Ks[2][64][72];

    const int g  = blockIdx.x;
    const int r0 = blockIdx.y * 128;
    const int t  = threadIdx.x;
    const int w  = t >> 6;
    const int l  = t & 63;
    const int lr = l & 15;
    const int lg = l >> 4;
    const int srow0 = (t*2)   >> 3, ssub0 = ((t*2)   & 7) * 8;
    const int srow1 = (t*2+1) >> 3, ssub1 = ((t*2+1) & 7) * 8;

    s16x8 qf[2][2];
#pragma unroll
    for (int rf = 0; rf < 2; ++rf) {
        const ushort_t* qrow = qb + ((size_t)(g*2048 + r0 + w*32 + rf*16 + lr)) * 64;
        qf[rf][0] = *reinterpret_cast<const s16x8*>(qrow + lg*8);
        qf[rf][1] = *reinterpret_cast<const s16x8*>(qrow + 32 + lg*8);
    }

    // prologue: stage chunk 0
    *reinterpret_cast<s16x8*>(&Ks[0][srow0][ssub0]) =
        *reinterpret_cast<const s16x8*>(kb + ((size_t)(g*2048 + srow0))*64 + ssub0);
    *reinterpret_cast<s16x8*>(&Ks[0][srow1][ssub1]) =
        *reinterpret_cast<const s16x8*>(kb + ((size_t)(g*2048 + srow1))*64 + ssub1);
    __syncthreads();

    float lsum[2][4] = {};
    int cur = 0;

    for (int jc = 0; jc < 32; ++jc) {
        s16x8 nk0, nk1;
        if (jc < 31) {   // issue next-chunk loads early (hidden under MFMA)
            nk0 = *reinterpret_cast<const s16x8*>(kb + ((size_t)(g*2048 + (jc+1)*64 + srow0))*64 + ssub0);
            nk1 = *reinterpret_cast<const s16x8*>(kb + ((size_t)(g*2048 + (jc+1)*64 + srow1))*64 + ssub1);
        }
#pragma unroll
        for (int jf = 0; jf < 4; ++jf) {
            s16x8 b0 = *reinterpret_cast<const s16x8*>(&Ks[cur][jf*16 + lr][lg*8]);
            s16x8 b1 = *reinterpret_cast<const s16x8*>(&Ks[cur][jf*16 + lr][32 + lg*8]);
#pragma unroll
            for (int rf = 0; rf < 2; ++rf) {
                f32x4 sv = {};
                sv = __builtin_amdgcn_mfma_f32_16x16x32_bf16(qf[rf][0], b0, sv, 0, 0, 0);
                sv = __builtin_amdgcn_mfma_f32_16x16x32_bf16(qf[rf][1], b1, sv, 0, 0, 0);
#pragma unroll
                for (int r = 0; r < 4; ++r)
                    lsum[rf][r] += __expf(sv[r] * 0.5f);
            }
        }
        if (jc < 31) {
            *reinterpret_cast<s16x8*>(&Ks[cur^1][srow0][ssub0]) = nk0;
            *reinterpret_cast<s16x8*>(&Ks[cur^1][srow1][ssub1]) = nk1;
        }
        __syncthreads();
        cur ^= 1;
    }

#pragma unroll
    for (int rf = 0; rf < 2; ++rf)
#pragma unroll
        for (int r = 0; r < 4; ++r) {
            float v = lsum[rf][r];
            v += __shfl_xor(v, 1); v += __shfl_xor(v, 2);
            v += __shfl_xor(v, 4); v += __shfl_xor(v, 8);
            if (lr == 0)
                invb[(size_t)g*2048 + r0 + w*32 + rf*16 + lg*4 + r] = 1.f / v;
        }
}

// ---------------------------------------------------------------------------
// attn_main: single QK^T pass. Double-buffered K/V, async-split staging,
// 1 barrier per chunk (Ps is same-wave: no barrier between QK^T and PV).
// ---------------------------------------------------------------------------
__global__ __launch_bounds__(256) void attn_main(
    const ushort_t* __restrict__ qb, const ushort_t* __restrict__ kb,
    const ushort_t* __restrict__ vt, const float* __restrict__ invb,
    float* __restrict__ attn, ushort_t* __restrict__ ctxb)
{
    __shared__ ushort_t Ks[2][64][72];
    __shared__ ushort_t Vs[2][64][72];
    __shared__ ushort_t Ps[64][72];

    const int g  = blockIdx.x;
    const int r0 = blockIdx.y * 64;
    const int t  = threadIdx.x;
    const int w  = t >> 6;
    const int l  = t & 63;
    const int lr = l & 15;
    const int lg = l >> 4;
    const int srow0 = (t*2)   >> 3, ssub0 = ((t*2)   & 7) * 8;
    const int srow1 = (t*2+1) >> 3, ssub1 = ((t*2+1) & 7) * 8;

    s16x8 qf0, qf1;
    {
        const ushort_t* qrow = qb + ((size_t)(g*2048 + r0 + w*16 + lr)) * 64;
        qf0 = *reinterpret_cast<const s16x8*>(qrow + lg*8);
        qf1 = *reinterpret_cast<const s16x8*>(qrow + 32 + lg*8);
    }

    float inv[4];
#pragma unroll
    for (int r = 0; r < 4; ++r)
        inv[r] = invb[(size_t)g*2048 + r0 + w*16 + lg*4 + r];

    // prologue: stage chunk 0 (K and V^T)
    *reinterpret_cast<s16x8*>(&Ks[0][srow0][ssub0]) =
        *reinterpret_cast<const s16x8*>(kb + ((size_t)(g*2048 + srow0))*64 + ssub0);
    *reinterpret_cast<s16x8*>(&Ks[0][srow1][ssub1]) =
        *reinterpret_cast<const s16x8*>(kb + ((size_t)(g*2048 + srow1))*64 + ssub1);
    *reinterpret_cast<s16x8*>(&Vs[0][srow0][ssub0]) =
        *reinterpret_cast<const s16x8*>(vt + ((size_t)(g*64 + srow0))*2048 + ssub0);
    *reinterpret_cast<s16x8*>(&Vs[0][srow1][ssub1]) =
        *reinterpret_cast<const s16x8*>(vt + ((size_t)(g*64 + srow1))*2048 + ssub1);
    __syncthreads();

    f32x4 ctx[4] = {};
    int cur = 0;

    for (int jc = 0; jc < 32; ++jc) {
        // issue next-chunk loads early — latency hides under QK^T+PV
        s16x8 nk0, nk1, nv0, nv1;
        if (jc < 31) {
            nk0 = *reinterpret_cast<const s16x8*>(kb + ((size_t)(g*2048 + (jc+1)*64 + srow0))*64 + ssub0);
            nk1 = *reinterpret_cast<const s16x8*>(kb + ((size_t)(g*2048 + (jc+1)*64 + srow1))*64 + ssub1);
            nv0 = *reinterpret_cast<const s16x8*>(vt + ((size_t)(g*64 + srow0))*2048 + (jc+1)*64 + ssub0);
            nv1 = *reinterpret_cast<const s16x8*>(vt + ((size_t)(g*64 + srow1))*2048 + (jc+1)*64 + ssub1);
        }

        // phase A: QK^T -> exp -> attention store + Ps (own wave rows only)
#pragma unroll
        for (int jf = 0; jf < 4; ++jf) {
            s16x8 b0 = *reinterpret_cast<const s16x8*>(&Ks[cur][jf*16 + lr][lg*8]);
            s16x8 b1 = *reinterpret_cast<const s16x8*>(&Ks[cur][jf*16 + lr][32 + lg*8]);
            f32x4 s = {};
            s = __builtin_amdgcn_mfma_f32_16x16x32_bf16(qf0, b0, s, 0, 0, 0);
            s = __builtin_amdgcn_mfma_f32_16x16x32_bf16(qf1, b1, s, 0, 0, 0);
#pragma unroll
            for (int r = 0; r < 4; ++r) {
                float e = __expf(s[r] * 0.5f);
                attn[(size_t)g*Lseq*Lseq + (size_t)(r0 + w*16 + lg*4 + r)*Lseq
                     + jc*64 + jf*16 + lr] = e * inv[r];
                Ps[w*16 + lg*4 + r][jf*16 + lr] = f2bf(e);
            }
        }

        // phase B: PV. Ps rows [w*16, w*16+16) were written by THIS wave in
        // phase A — lgkmcnt ordering suffices, no workgroup barrier.
#pragma unroll
        for (int kk = 0; kk < 2; ++kk) {
            s16x8 pa = *reinterpret_cast<const s16x8*>(&Ps[w*16 + lr][kk*32 + lg*8]);
#pragma unroll
            for (int ni = 0; ni < 4; ++ni) {
                s16x8 bv = *reinterpret_cast<const s16x8*>(&Vs[cur][ni*16 + lr][kk*32 + lg*8]);
                ctx[ni] = __builtin_amdgcn_mfma_f32_16x16x32_bf16(pa, bv, ctx[ni], 0, 0, 0);
            }
        }

        // write next chunk into the other buffer; single barrier per chunk
        if (jc < 31) {
            *reinterpret_cast<s16x8*>(&Ks[cur^1][srow0][ssub0]) = nk0;
            *reinterpret_cast<s16x8*>(&Ks[cur^1][srow1][ssub1]) = nk1;
            *reinterpret_cast<s16x8*>(&Vs[cur^1][srow0][ssub0]) = nv0;
            *reinterpret_cast<s16x8*>(&Vs[cur^1][srow1][ssub1]) = nv1;
        }
        __syncthreads();
        cur ^= 1;
    }

    // ctx write — FLAT VIEW: g*L*64 + l2*64 + d2
#pragma unroll
    for (int ni = 0; ni < 4; ++ni)
#pragma unroll
        for (int r = 0; r < 4; ++r) {
            int l2 = r0 + w*16 + lg*4 + r;
            int d2 = ni*16 + lr;
            ctxb[(size_t)g*Lseq*64 + (size_t)l2*64 + d2] = f2bf(ctx[ni][r] * inv[r]);
        }
}

// ---------------------------------------------------------------------------
// LayerNorm over D=1024, one block per row, in-place.
// ---------------------------------------------------------------------------
__global__ __launch_bounds__(256) void ln_kernel(
    float* __restrict__ x, const float* __restrict__ gamma,
    const float* __restrict__ beta, float* __restrict__ out)
{
    const int row = blockIdx.x;
    const int t   = threadIdx.x;
    const int c   = t * 4;

    float4 v = *reinterpret_cast<const float4*>(x + (size_t)row * Dmodel + c);
    float s  = v.x + v.y + v.z + v.w;
    float s2 = v.x*v.x + v.y*v.y + v.z*v.z + v.w*v.w;
    for (int off = 1; off < 64; off <<= 1) {
        s  += __shfl_xor(s, off);
        s2 += __shfl_xor(s2, off);
    }
    __shared__ float ssum[4], ssum2[4];
    int wid = t >> 6;
    if ((t & 63) == 0) { ssum[wid] = s; ssum2[wid] = s2; }
    __syncthreads();
    s  = ssum[0] + ssum[1] + ssum[2] + ssum[3];
    s2 = ssum2[0] + ssum2[1] + ssum2[2] + ssum2[3];

    float mean = s * (1.f / Dmodel);
    float var  = s2 * (1.f / Dmodel) - mean * mean;
    float rstd = rsqrtf(var + EPS_LN);

    float4 gv = *reinterpret_cast<const float4*>(gamma + c);
    float4 bv = *reinterpret_cast<const float4*>(beta + c);
    float4 o;
    o.x = (v.x - mean) * rstd * gv.x + bv.x;
    o.y = (v.y - mean) * rstd * gv.y + bv.y;
    o.z = (v.z - mean) * rstd * gv.z + bv.z;
    o.w = (v.w - mean) * rstd * gv.w + bv.w;
    *reinterpret_cast<float4*>(out + (size_t)row * Dmodel + c) = o;
}

// ---------------------------------------------------------------------------
extern "C" void kernel_launch(void* const* d_in, const int* in_sizes, int n_in,
                              void* d_out, int out_size, void* d_ws, size_t ws_size,
                              hipStream_t stream)
{
    const float* key   = (const float*)d_in[0];
    const float* value = (const float*)d_in[1];
    const float* query = (const float*)d_in[2];
    const float* Wq    = (const float*)d_in[3];
    const float* bq    = (const float*)d_in[4];
    const float* Wk    = (const float*)d_in[5];
    const float* bk    = (const float*)d_in[6];
    const float* Wv    = (const float*)d_in[7];
    const float* bv    = (const float*)d_in[8];
    const float* Wo    = (const float*)d_in[9];
    const float* bo    = (const float*)d_in[10];
    const float* gamma = (const float*)d_in[11];
    const float* beta  = (const float*)d_in[12];

    float* out  = (float*)d_out;
    float* attn = out + (size_t)MROWS * Dmodel;

    const size_t M1 = 1024 * 1024;
    ushort_t* ws   = (ushort_t*)d_ws;
    ushort_t* qb   = ws;                 // 4M
    ushort_t* kb   = ws + 4  * M1;       // 4M
    ushort_t* vb   = ws + 8  * M1;       // 4M
    ushort_t* vt   = ws + 12 * M1;       // 4M
    ushort_t* qx   = ws + 16 * M1;       // 4M (reused as ctxb after Q-GEMM)
    ushort_t* kx   = ws + 20 * M1;       // 4M (reused as invb after K-GEMM)
    ushort_t* vx   = ws + 24 * M1;       // 4M
    ushort_t* wqx  = ws + 28 * M1;       // 1M
    ushort_t* wkx  = ws + 29 * M1;       // 1M
    ushort_t* wvx  = ws + 30 * M1;       // 1M
    ushort_t* wox  = ws + 31 * M1;       // 1M  -> 64 MB total
    ushort_t* ctxb = qx;
    float*    invb = (float*)kx;

    // 1. convert everything to bf16
    CvtArgs ca;
    ca.src[0]=query; ca.dst[0]=qx;  ca.n8[0]=(int)(4*M1/8);
    ca.src[1]=key;   ca.dst[1]=kx;  ca.n8[1]=(int)(4*M1/8);
    ca.src[2]=value; ca.dst[2]=vx;  ca.n8[2]=(int)(4*M1/8);
    ca.src[3]=Wq;    ca.dst[3]=wqx; ca.n8[3]=(int)(M1/8);
    ca.src[4]=Wk;    ca.dst[4]=wkx; ca.n8[4]=(int)(M1/8);
    ca.src[5]=Wv;    ca.dst[5]=wvx; ca.n8[5]=(int)(M1/8);
    ca.src[6]=Wo;    ca.dst[6]=wox; ca.n8[6]=(int)(M1/8);
    cvt_bf16<<<dim3(512, 7), 256, 0, stream>>>(ca);

    // 2. fused Q/K/V projections (z-indexed)
    QkvArgs qa;
    qa.A[0]=qx; qa.W[0]=wqx; qa.bias[0]=bq; qa.out[0]=qb;
    qa.A[1]=kx; qa.W[1]=wkx; qa.bias[1]=bk; qa.out[1]=kb;
    qa.A[2]=vx; qa.W[2]=wvx; qa.bias[2]=bv; qa.out[2]=vb;
    gemm_qkv<<<dim3(Dmodel/64, MROWS/128, 3), 256, 0, stream>>>(qa);

    // 3. V transpose
    transpose_v<<<dim3(NGRP, Lseq/64), 256, 0, stream>>>(vb, vt);

    // 4. softmax denominators
    attn_stats<<<dim3(NGRP, Lseq/128), 256, 0, stream>>>(qb, kb, invb);

    // 5. attention write + PV in one pass
    attn_main<<<dim3(NGRP, Lseq/64), 256, 0, stream>>>(qb, kb, vt, invb, attn, ctxb);

    // 6. output projection + residual
    gemm_o<<<dim3(Dmodel/64, MROWS/128), 256, 0, stream>>>(ctxb, wox, bo, query, out);

    // 7. LayerNorm
    ln_kernel<<<dim3(MROWS), 256, 0, stream>>>(out, gamma, beta, out);
}

// Round 6
// 306.707 us; speedup vs baseline: 6.1463x; 1.0928x over previous
//
#include <hip/hip_runtime.h>
#include <cstddef>
#include <cstdint>

#define Lseq   2048
#define Dmodel 1024
#define NGRP   32          // B*H
#define MROWS  4096        // B*L
#define EPS_LN 1e-5f

typedef short  s16x8 __attribute__((ext_vector_type(8)));
typedef float  f32x4 __attribute__((ext_vector_type(4)));
typedef unsigned short ushort_t;

__device__ __forceinline__ ushort_t f2bf(float f) {
    union { float f; unsigned u; } v; v.f = f;
    unsigned r = v.u + 0x7FFFu + ((v.u >> 16) & 1u);   // round-to-nearest-even
    return (ushort_t)(r >> 16);
}

// packed f32x2 -> bf16x2 (RTNE, same rounding as f2bf)
__device__ __forceinline__ unsigned cvt_pk_bf16(float lo, float hi) {
    unsigned r;
    asm("v_cvt_pk_bf16_f32 %0, %1, %2" : "=v"(r) : "v"(lo), "v"(hi));
    return r;
}

// CK-idiom addrspace casts (uintptr round-trip; folded by InferAddressSpaces)
__device__ __forceinline__ void gld16(const ushort_t* g, ushort_t* lds) {
    __builtin_amdgcn_global_load_lds(
        (const __attribute__((address_space(1))) unsigned int*)(uintptr_t)g,
        (__attribute__((address_space(3))) unsigned int*)(uintptr_t)lds,
        16, 0, 0);
}

// ---------------------------------------------------------------------------
// Pre-convert fp32 -> bf16 for Q/K/V inputs and the 4 weight matrices.
// ---------------------------------------------------------------------------
struct CvtArgs {
    const float* src[7];
    ushort_t*    dst[7];
    int          n8[7];
};

__global__ __launch_bounds__(256) void cvt_bf16(CvtArgs a)
{
    const int ti = blockIdx.y;
    const float* __restrict__ s = a.src[ti];
    ushort_t* __restrict__    d = a.dst[ti];
    const int n8 = a.n8[ti];
    for (int i = blockIdx.x * 256 + threadIdx.x; i < n8; i += gridDim.x * 256) {
        float4 x0 = reinterpret_cast<const float4*>(s)[i * 2];
        float4 x1 = reinterpret_cast<const float4*>(s)[i * 2 + 1];
        s16x8 o;
        o[0]=f2bf(x0.x); o[1]=f2bf(x0.y); o[2]=f2bf(x0.z); o[3]=f2bf(x0.w);
        o[4]=f2bf(x1.x); o[5]=f2bf(x1.y); o[6]=f2bf(x1.z); o[7]=f2bf(x1.w);
        reinterpret_cast<s16x8*>(d)[i] = o;
    }
}

// ---------------------------------------------------------------------------
// Shared GEMM body: out[M,N] = A[M,1024] @ W[N,1024]^T + bias (+resid)
// Tile 128x128, BK=32, 256 thr (4 waves 2x2), global_load_lds width-16.
// ---------------------------------------------------------------------------
template<bool OUT_BF16>
__device__ __forceinline__ void gemm_body(
    const ushort_t* __restrict__ A, const ushort_t* __restrict__ W,
    const float* __restrict__ bias, const float* __restrict__ resid,
    void* __restrict__ outv, ushort_t* As, ushort_t* Bs)
{
    const int t  = threadIdx.x;
    const int m0 = blockIdx.y * 128;
    const int n0 = blockIdx.x * 128;
    const int w  = t >> 6;
    const int l  = t & 63;
    const int lr = l & 15;
    const int lg = l >> 4;
    const int wm = w >> 1, wn = w & 1;

    const ushort_t* gA  = A + (size_t)(m0 + w * 32 + (l >> 2)) * 1024 + (l & 3) * 8;
    const ushort_t* gA2 = gA + (size_t)16 * 1024;
    const ushort_t* gB  = W + (size_t)(n0 + w * 32 + (l >> 2)) * 1024 + (l & 3) * 8;
    const ushort_t* gB2 = gB + (size_t)16 * 1024;
    ushort_t* lA  = &As[(w * 32) * 32];
    ushort_t* lA2 = &As[(w * 32 + 16) * 32];
    ushort_t* lB  = &Bs[(w * 32) * 32];
    ushort_t* lB2 = &Bs[(w * 32 + 16) * 32];

    f32x4 acc[4][4] = {};

    for (int k0 = 0; k0 < 1024; k0 += 32) {
        gld16(gA  + k0, lA);
        gld16(gA2 + k0, lA2);
        gld16(gB  + k0, lB);
        gld16(gB2 + k0, lB2);
        __syncthreads();

        s16x8 af[4], bf[4];
#pragma unroll
        for (int mi = 0; mi < 4; ++mi)
            af[mi] = *reinterpret_cast<const s16x8*>(&As[(wm * 64 + mi * 16 + lr) * 32 + lg * 8]);
#pragma unroll
        for (int ni = 0; ni < 4; ++ni)
            bf[ni] = *reinterpret_cast<const s16x8*>(&Bs[(wn * 64 + ni * 16 + lr) * 32 + lg * 8]);
#pragma unroll
        for (int mi = 0; mi < 4; ++mi)
#pragma unroll
            for (int ni = 0; ni < 4; ++ni)
                acc[mi][ni] = __builtin_amdgcn_mfma_f32_16x16x32_bf16(af[mi], bf[ni], acc[mi][ni], 0, 0, 0);
        __syncthreads();
    }

#pragma unroll
    for (int mi = 0; mi < 4; ++mi)
#pragma unroll
        for (int ni = 0; ni < 4; ++ni)
#pragma unroll
            for (int r = 0; r < 4; ++r) {
                int row = m0 + wm * 64 + mi * 16 + lg * 4 + r;
                int col = n0 + wn * 64 + ni * 16 + lr;
                float v = acc[mi][ni][r] + bias[col];
                if (OUT_BF16) {
                    ((ushort_t*)outv)[(size_t)row * 1024 + col] = f2bf(v);
                } else {
                    v += resid[(size_t)row * 1024 + col];
                    ((float*)outv)[(size_t)row * 1024 + col] = v;
                }
            }
}

struct QkvArgs {
    const ushort_t* A[3];
    const ushort_t* W[3];
    const float*    bias[3];
    ushort_t*       out[3];
};

__global__ __launch_bounds__(256) void gemm_qkv(QkvArgs a)
{
    __shared__ ushort_t As[128 * 32];
    __shared__ ushort_t Bs[128 * 32];
    const int z = blockIdx.z;
    gemm_body<true>(a.A[z], a.W[z], a.bias[z], nullptr, a.out[z], As, Bs);
}

__global__ __launch_bounds__(256) void gemm_o(
    const ushort_t* __restrict__ A, const ushort_t* __restrict__ W,
    const float* __restrict__ bias, const float* __restrict__ resid,
    float* __restrict__ out)
{
    __shared__ ushort_t As[128 * 32];
    __shared__ ushort_t Bs[128 * 32];
    gemm_body<false>(A, W, bias, resid, out, As, Bs);
}

// ---------------------------------------------------------------------------
// V transpose: vb[32][2048][64] -> vt[32][64][2048]  (bf16, flat-view groups)
// ---------------------------------------------------------------------------
__global__ __launch_bounds__(256) void transpose_v(
    const ushort_t* __restrict__ vb, ushort_t* __restrict__ vt)
{
    __shared__ ushort_t tile[64][72];
    const int g  = blockIdx.x;
    const int lt = blockIdx.y;
    const int t  = threadIdx.x;
#pragma unroll
    for (int it = 0; it < 2; ++it) {
        int s = t * 2 + it, row = s >> 3, sub = (s & 7) * 8;
        *reinterpret_cast<s16x8*>(&tile[row][sub]) =
            *reinterpret_cast<const s16x8*>(vb + ((size_t)(g*2048 + lt*64 + row))*64 + sub);
    }
    __syncthreads();
#pragma unroll
    for (int it = 0; it < 2; ++it) {
        int s = t * 2 + it, drow = s >> 3, sub = (s & 7) * 8;
        s16x8 o;
#pragma unroll
        for (int j = 0; j < 8; ++j) o[j] = (short)tile[sub + j][drow];
        *reinterpret_cast<s16x8*>(vt + ((size_t)(g*64 + drow))*2048 + lt*64 + sub) = o;
    }
}

// ---------------------------------------------------------------------------
// attn_stats: row sums of exp(0.5*QK^T) -> invb (1/sum).  128 q-rows/block.
// Double-buffered K staging, 1 barrier per 64-key chunk.
// ---------------------------------------------------------------------------
__global__ __launch_bounds__(256) void attn_stats(
    const ushort_t* __restrict__ qb, const ushort_t* __restrict__ kb,
    float* __restrict__ invb)
{
    __shared__ ushort_t Ks[2][64][72];

    const int g  = blockIdx.x;
    const int r0 = blockIdx.y * 128;
    const int t  = threadIdx.x;
    const int w  = t >> 6;
    const int l  = t & 63;
    const int lr = l & 15;
    const int lg = l >> 4;
    const int srow0 = (t*2)   >> 3, ssub0 = ((t*2)   & 7) * 8;
    const int srow1 = (t*2+1) >> 3, ssub1 = ((t*2+1) & 7) * 8;

    s16x8 qf[2][2];
#pragma unroll
    for (int rf = 0; rf < 2; ++rf) {
        const ushort_t* qrow = qb + ((size_t)(g*2048 + r0 + w*32 + rf*16 + lr)) * 64;
        qf[rf][0] = *reinterpret_cast<const s16x8*>(qrow + lg*8);
        qf[rf][1] = *reinterpret_cast<const s16x8*>(qrow + 32 + lg*8);
    }

    *reinterpret_cast<s16x8*>(&Ks[0][srow0][ssub0]) =
        *reinterpret_cast<const s16x8*>(kb + ((size_t)(g*2048 + srow0))*64 + ssub0);
    *reinterpret_cast<s16x8*>(&Ks[0][srow1][ssub1]) =
        *reinterpret_cast<const s16x8*>(kb + ((size_t)(g*2048 + srow1))*64 + ssub1);
    __syncthreads();

    float lsum[2][4] = {};
    int cur = 0;

    for (int jc = 0; jc < 32; ++jc) {
        s16x8 nk0, nk1;
        if (jc < 31) {
            nk0 = *reinterpret_cast<const s16x8*>(kb + ((size_t)(g*2048 + (jc+1)*64 + srow0))*64 + ssub0);
            nk1 = *reinterpret_cast<const s16x8*>(kb + ((size_t)(g*2048 + (jc+1)*64 + srow1))*64 + ssub1);
        }
#pragma unroll
        for (int jf = 0; jf < 4; ++jf) {
            s16x8 b0 = *reinterpret_cast<const s16x8*>(&Ks[cur][jf*16 + lr][lg*8]);
            s16x8 b1 = *reinterpret_cast<const s16x8*>(&Ks[cur][jf*16 + lr][32 + lg*8]);
#pragma unroll
            for (int rf = 0; rf < 2; ++rf) {
                f32x4 sv = {};
                sv = __builtin_amdgcn_mfma_f32_16x16x32_bf16(qf[rf][0], b0, sv, 0, 0, 0);
                sv = __builtin_amdgcn_mfma_f32_16x16x32_bf16(qf[rf][1], b1, sv, 0, 0, 0);
#pragma unroll
                for (int r = 0; r < 4; ++r)
                    lsum[rf][r] += __expf(sv[r] * 0.5f);
            }
        }
        if (jc < 31) {
            *reinterpret_cast<s16x8*>(&Ks[cur^1][srow0][ssub0]) = nk0;
            *reinterpret_cast<s16x8*>(&Ks[cur^1][srow1][ssub1]) = nk1;
        }
        __syncthreads();
        cur ^= 1;
    }

#pragma unroll
    for (int rf = 0; rf < 2; ++rf)
#pragma unroll
        for (int r = 0; r < 4; ++r) {
            float v = lsum[rf][r];
            v += __shfl_xor(v, 1); v += __shfl_xor(v, 2);
            v += __shfl_xor(v, 4); v += __shfl_xor(v, 8);
            if (lr == 0)
                invb[(size_t)g*2048 + r0 + w*32 + rf*16 + lg*4 + r] = 1.f / v;
        }
}

// ---------------------------------------------------------------------------
// attn_main: single QK^T pass, SWAPPED operands (mfma(K,Q)) so each lane
// holds 4 consecutive keys of one q-row -> float4 attention stores and
// packed-b64 Ps writes. Double-buffered K/V, 1 barrier per chunk.
// ---------------------------------------------------------------------------
__global__ __launch_bounds__(256) void attn_main(
    const ushort_t* __restrict__ qb, const ushort_t* __restrict__ kb,
    const ushort_t* __restrict__ vt, const float* __restrict__ invb,
    float* __restrict__ attn, ushort_t* __restrict__ ctxb)
{
    __shared__ ushort_t Ks[2][64][72];
    __shared__ ushort_t Vs[2][64][72];
    __shared__ ushort_t Ps[64][72];

    const int g  = blockIdx.x;
    const int r0 = blockIdx.y * 64;
    const int t  = threadIdx.x;
    const int w  = t >> 6;
    const int l  = t & 63;
    const int lr = l & 15;
    const int lg = l >> 4;
    const int srow0 = (t*2)   >> 3, ssub0 = ((t*2)   & 7) * 8;
    const int srow1 = (t*2+1) >> 3, ssub1 = ((t*2+1) & 7) * 8;

    s16x8 qf0, qf1;
    {
        const ushort_t* qrow = qb + ((size_t)(g*2048 + r0 + w*16 + lr)) * 64;
        qf0 = *reinterpret_cast<const s16x8*>(qrow + lg*8);
        qf1 = *reinterpret_cast<const s16x8*>(qrow + 32 + lg*8);
    }

    // swapped layout: this lane's q-row is (w*16 + lr)
    const float inv_s = invb[(size_t)g*2048 + r0 + w*16 + lr];
    float* arow = attn + (size_t)g*Lseq*Lseq + (size_t)(r0 + w*16 + lr)*Lseq + lg*4;

    *reinterpret_cast<s16x8*>(&Ks[0][srow0][ssub0]) =
        *reinterpret_cast<const s16x8*>(kb + ((size_t)(g*2048 + srow0))*64 + ssub0);
    *reinterpret_cast<s16x8*>(&Ks[0][srow1][ssub1]) =
        *reinterpret_cast<const s16x8*>(kb + ((size_t)(g*2048 + srow1))*64 + ssub1);
    *reinterpret_cast<s16x8*>(&Vs[0][srow0][ssub0]) =
        *reinterpret_cast<const s16x8*>(vt + ((size_t)(g*64 + srow0))*2048 + ssub0);
    *reinterpret_cast<s16x8*>(&Vs[0][srow1][ssub1]) =
        *reinterpret_cast<const s16x8*>(vt + ((size_t)(g*64 + srow1))*2048 + ssub1);
    __syncthreads();

    f32x4 ctx[4] = {};
    int cur = 0;

    for (int jc = 0; jc < 32; ++jc) {
        s16x8 nk0, nk1, nv0, nv1;
        if (jc < 31) {
            nk0 = *reinterpret_cast<const s16x8*>(kb + ((size_t)(g*2048 + (jc+1)*64 + srow0))*64 + ssub0);
            nk1 = *reinterpret_cast<const s16x8*>(kb + ((size_t)(g*2048 + (jc+1)*64 + srow1))*64 + ssub1);
            nv0 = *reinterpret_cast<const s16x8*>(vt + ((size_t)(g*64 + srow0))*2048 + (jc+1)*64 + ssub0);
            nv1 = *reinterpret_cast<const s16x8*>(vt + ((size_t)(g*64 + srow1))*2048 + (jc+1)*64 + ssub1);
        }

        // phase A: S^T = K·Q^T -> lane holds keys {jf*16+4lg..+3} of q-row lr
#pragma unroll
        for (int jf = 0; jf < 4; ++jf) {
            s16x8 a0 = *reinterpret_cast<const s16x8*>(&Ks[cur][jf*16 + lr][lg*8]);
            s16x8 a1 = *reinterpret_cast<const s16x8*>(&Ks[cur][jf*16 + lr][32 + lg*8]);
            f32x4 s = {};
            s = __builtin_amdgcn_mfma_f32_16x16x32_bf16(a0, qf0, s, 0, 0, 0);
            s = __builtin_amdgcn_mfma_f32_16x16x32_bf16(a1, qf1, s, 0, 0, 0);

            float e0 = __expf(s[0] * 0.5f);
            float e1 = __expf(s[1] * 0.5f);
            float e2 = __expf(s[2] * 0.5f);
            float e3 = __expf(s[3] * 0.5f);

            f32x4 o;
            o[0] = e0 * inv_s; o[1] = e1 * inv_s; o[2] = e2 * inv_s; o[3] = e3 * inv_s;
            *reinterpret_cast<f32x4*>(arow + jc*64 + jf*16) = o;

            unsigned p01 = cvt_pk_bf16(e0, e1);
            unsigned p23 = cvt_pk_bf16(e2, e3);
            uint2 pk; pk.x = p01; pk.y = p23;
            *reinterpret_cast<uint2*>(&Ps[w*16 + lr][jf*16 + lg*4]) = pk;
        }

        // phase B: PV. Ps rows [w*16, w*16+16) were written by THIS wave —
        // lgkmcnt ordering suffices, no workgroup barrier.
#pragma unroll
        for (int kk = 0; kk < 2; ++kk) {
            s16x8 pa = *reinterpret_cast<const s16x8*>(&Ps[w*16 + lr][kk*32 + lg*8]);
#pragma unroll
            for (int ni = 0; ni < 4; ++ni) {
                s16x8 bv = *reinterpret_cast<const s16x8*>(&Vs[cur][ni*16 + lr][kk*32 + lg*8]);
                ctx[ni] = __builtin_amdgcn_mfma_f32_16x16x32_bf16(pa, bv, ctx[ni], 0, 0, 0);
            }
        }

        if (jc < 31) {
            *reinterpret_cast<s16x8*>(&Ks[cur^1][srow0][ssub0]) = nk0;
            *reinterpret_cast<s16x8*>(&Ks[cur^1][srow1][ssub1]) = nk1;
            *reinterpret_cast<s16x8*>(&Vs[cur^1][srow0][ssub0]) = nv0;
            *reinterpret_cast<s16x8*>(&Vs[cur^1][srow1][ssub1]) = nv1;
        }
        __syncthreads();
        cur ^= 1;
    }

    // ctx write — FLAT VIEW: g*L*64 + l2*64 + d2.  PV output layout:
    // lane holds q-rows lg*4+r, dim d2 = ni*16+lr.  Normalize per-row.
    {
        // inv for q-row (w*16 + lg*4 + r): fetch 4 values
#pragma unroll
        for (int ni = 0; ni < 4; ++ni)
#pragma unroll
            for (int r = 0; r < 4; ++r) {
                int l2 = r0 + w*16 + lg*4 + r;
                int d2 = ni*16 + lr;
                float iv = invb[(size_t)g*2048 + l2];
                ctxb[(size_t)g*Lseq*64 + (size_t)l2*64 + d2] = f2bf(ctx[ni][r] * iv);
            }
    }
}

// ---------------------------------------------------------------------------
// LayerNorm over D=1024, one block per row, in-place.
// ---------------------------------------------------------------------------
__global__ __launch_bounds__(256) void ln_kernel(
    float* __restrict__ x, const float* __restrict__ gamma,
    const float* __restrict__ beta, float* __restrict__ out)
{
    const int row = blockIdx.x;
    const int t   = threadIdx.x;
    const int c   = t * 4;

    float4 v = *reinterpret_cast<const float4*>(x + (size_t)row * Dmodel + c);
    float s  = v.x + v.y + v.z + v.w;
    float s2 = v.x*v.x + v.y*v.y + v.z*v.z + v.w*v.w;
    for (int off = 1; off < 64; off <<= 1) {
        s  += __shfl_xor(s, off);
        s2 += __shfl_xor(s2, off);
    }
    __shared__ float ssum[4], ssum2[4];
    int wid = t >> 6;
    if ((t & 63) == 0) { ssum[wid] = s; ssum2[wid] = s2; }
    __syncthreads();
    s  = ssum[0] + ssum[1] + ssum[2] + ssum[3];
    s2 = ssum2[0] + ssum2[1] + ssum2[2] + ssum2[3];

    float mean = s * (1.f / Dmodel);
    float var  = s2 * (1.f / Dmodel) - mean * mean;
    float rstd = rsqrtf(var + EPS_LN);

    float4 gv = *reinterpret_cast<const float4*>(gamma + c);
    float4 bv = *reinterpret_cast<const float4*>(beta + c);
    float4 o;
    o.x = (v.x - mean) * rstd * gv.x + bv.x;
    o.y = (v.y - mean) * rstd * gv.y + bv.y;
    o.z = (v.z - mean) * rstd * gv.z + bv.z;
    o.w = (v.w - mean) * rstd * gv.w + bv.w;
    *reinterpret_cast<float4*>(out + (size_t)row * Dmodel + c) = o;
}

// ---------------------------------------------------------------------------
extern "C" void kernel_launch(void* const* d_in, const int* in_sizes, int n_in,
                              void* d_out, int out_size, void* d_ws, size_t ws_size,
                              hipStream_t stream)
{
    const float* key   = (const float*)d_in[0];
    const float* value = (const float*)d_in[1];
    const float* query = (const float*)d_in[2];
    const float* Wq    = (const float*)d_in[3];
    const float* bq    = (const float*)d_in[4];
    const float* Wk    = (const float*)d_in[5];
    const float* bk    = (const float*)d_in[6];
    const float* Wv    = (const float*)d_in[7];
    const float* bv    = (const float*)d_in[8];
    const float* Wo    = (const float*)d_in[9];
    const float* bo    = (const float*)d_in[10];
    const float* gamma = (const float*)d_in[11];
    const float* beta  = (const float*)d_in[12];

    float* out  = (float*)d_out;
    float* attn = out + (size_t)MROWS * Dmodel;

    const size_t M1 = 1024 * 1024;
    ushort_t* ws   = (ushort_t*)d_ws;
    ushort_t* qb   = ws;                 // 4M
    ushort_t* kb   = ws + 4  * M1;       // 4M
    ushort_t* vb   = ws + 8  * M1;       // 4M
    ushort_t* vt   = ws + 12 * M1;       // 4M
    ushort_t* qx   = ws + 16 * M1;       // 4M (reused as ctxb after Q-GEMM)
    ushort_t* kx   = ws + 20 * M1;       // 4M (reused as invb after K-GEMM)
    ushort_t* vx   = ws + 24 * M1;       // 4M
    ushort_t* wqx  = ws + 28 * M1;       // 1M
    ushort_t* wkx  = ws + 29 * M1;       // 1M
    ushort_t* wvx  = ws + 30 * M1;       // 1M
    ushort_t* wox  = ws + 31 * M1;       // 1M  -> 64 MB total
    ushort_t* ctxb = qx;
    float*    invb = (float*)kx;

    // 1. convert everything to bf16
    CvtArgs ca;
    ca.src[0]=query; ca.dst[0]=qx;  ca.n8[0]=(int)(4*M1/8);
    ca.src[1]=key;   ca.dst[1]=kx;  ca.n8[1]=(int)(4*M1/8);
    ca.src[2]=value; ca.dst[2]=vx;  ca.n8[2]=(int)(4*M1/8);
    ca.src[3]=Wq;    ca.dst[3]=wqx; ca.n8[3]=(int)(M1/8);
    ca.src[4]=Wk;    ca.dst[4]=wkx; ca.n8[4]=(int)(M1/8);
    ca.src[5]=Wv;    ca.dst[5]=wvx; ca.n8[5]=(int)(M1/8);
    ca.src[6]=Wo;    ca.dst[6]=wox; ca.n8[6]=(int)(M1/8);
    cvt_bf16<<<dim3(512, 7), 256, 0, stream>>>(ca);

    // 2. fused Q/K/V projections (z-indexed), 128x128 tiles
    QkvArgs qa;
    qa.A[0]=qx; qa.W[0]=wqx; qa.bias[0]=bq; qa.out[0]=qb;
    qa.A[1]=kx; qa.W[1]=wkx; qa.bias[1]=bk; qa.out[1]=kb;
    qa.A[2]=vx; qa.W[2]=wvx; qa.bias[2]=bv; qa.out[2]=vb;
    gemm_qkv<<<dim3(Dmodel/128, MROWS/128, 3), 256, 0, stream>>>(qa);

    // 3. V transpose
    transpose_v<<<dim3(NGRP, Lseq/64), 256, 0, stream>>>(vb, vt);

    // 4. softmax denominators
    attn_stats<<<dim3(NGRP, Lseq/128), 256, 0, stream>>>(qb, kb, invb);

    // 5. attention write + PV in one pass
    attn_main<<<dim3(NGRP, Lseq/64), 256, 0, stream>>>(qb, kb, vt, invb, attn, ctxb);

    // 6. output projection + residual, 128x128 tiles
    gemm_o<<<dim3(Dmodel/128, MROWS/128), 256, 0, stream>>>(ctxb, wox, bo, query, out);

    // 7. LayerNorm
    ln_kernel<<<dim3(MROWS), 256, 0, stream>>>(out, gamma, beta, out);
}